// Round 1
// baseline (821.551 us; speedup 1.0000x reference)
//
#include <hip/hip_runtime.h>
#include <math.h>

// SQP entropy-knapsack loss, MI355X (gfx950).
// One 1024-thread block per row; the 32000-f32 row is held in 8 float4
// registers per thread, so all 51 reduction passes are register+LDS only.

constexpr int C       = 32000;
constexpr int NV4     = C / 4;        // 8000 float4 per row
constexpr int TPB     = 1024;
constexpr float KF    = 5.0f;
constexpr int NITERS  = 50;
constexpr float NEGLOG2E = -1.4426950408889634f;

__device__ __forceinline__ float wsum(float v) {
#pragma unroll
    for (int o = 32; o > 0; o >>= 1) v += __shfl_xor(v, o, 64);
    return v;
}
__device__ __forceinline__ float wmax(float v) {
#pragma unroll
    for (int o = 32; o > 0; o >>= 1) v = fmaxf(v, __shfl_xor(v, o, 64));
    return v;
}
__device__ __forceinline__ float wmin(float v) {
#pragma unroll
    for (int o = 32; o > 0; o >>= 1) v = fminf(v, __shfl_xor(v, o, 64));
    return v;
}

// sigmoid(z + mid) where a = z*(-log2e), ms = mid*(-log2e):
//   = 1 / (1 + exp2(a + ms))
__device__ __forceinline__ float sig1(float a, float ms) {
    return __builtin_amdgcn_rcpf(1.0f + __builtin_amdgcn_exp2f(a + ms));
}
__device__ __forceinline__ float sig4(float4 a, float ms) {
    return sig1(a.x, ms) + sig1(a.y, ms) + sig1(a.z, ms) + sig1(a.w, ms);
}

__global__ __launch_bounds__(TPB, 1) void sqp_rows(
    const float* __restrict__ x, const int* __restrict__ y,
    float* __restrict__ row_loss)
{
    const int row  = blockIdx.x;
    const int t    = threadIdx.x;
    const int wid  = t >> 6;
    const int lane = t & 63;
    const float4* xr = reinterpret_cast<const float4*>(x + (size_t)row * C);
    const bool v7 = (t + 7 * TPB) < NV4;   // tail: last vec4 batch only t<832

    // ---- load row into registers (coalesced 16B/lane) ----
    float4 v[8];
#pragma unroll
    for (int i = 0; i < 7; ++i) v[i] = xr[t + i * TPB];
    v[7] = v7 ? xr[t + 7 * TPB] : make_float4(0.f, 0.f, 0.f, 0.f);

    // ---- row stats: sum of squares, max, min ----
    float ss = 0.f, mx = -INFINITY, mn = INFINITY;
#pragma unroll
    for (int i = 0; i < 7; ++i) {
        float4 a = v[i];
        ss += a.x*a.x + a.y*a.y + a.z*a.z + a.w*a.w;
        mx = fmaxf(mx, fmaxf(fmaxf(a.x, a.y), fmaxf(a.z, a.w)));
        mn = fminf(mn, fminf(fminf(a.x, a.y), fminf(a.z, a.w)));
    }
    if (v7) {
        float4 a = v[7];
        ss += a.x*a.x + a.y*a.y + a.z*a.z + a.w*a.w;
        mx = fmaxf(mx, fmaxf(fmaxf(a.x, a.y), fmaxf(a.z, a.w)));
        mn = fminf(mn, fminf(fminf(a.x, a.y), fminf(a.z, a.w)));
    }

    __shared__ float red[3][16];
    ss = wsum(ss); mx = wmax(mx); mn = wmin(mn);
    if (lane == 0) { red[0][wid] = ss; red[1][wid] = mx; red[2][wid] = mn; }
    __syncthreads();
    float tss = 0.f, tmx = -INFINITY, tmn = INFINITY;
#pragma unroll
    for (int w = 0; w < 16; ++w) {
        tss += red[0][w];
        tmx = fmaxf(tmx, red[1][w]);
        tmn = fminf(tmn, red[2][w]);
    }
    const float nrm = fmaxf(sqrtf(tss), 1e-12f);
    const float inv = 1.0f / nrm;
    float lo = -tmx * inv - 10.0f;
    float hi = -tmn * inv + 10.0f;

    // pre-scale registers into the exp2 domain: a_i = z_i * (-log2 e)
    const float sc = inv * NEGLOG2E;
#pragma unroll
    for (int i = 0; i < 8; ++i) {
        v[i].x *= sc; v[i].y *= sc; v[i].z *= sc; v[i].w *= sc;
    }
    __syncthreads();   // red[] reused below

    // ---- 50 bisection iterations, all in registers ----
    for (int it = 0; it < NITERS; ++it) {
        const float mid = 0.5f * (lo + hi);
        const float ms  = mid * NEGLOG2E;
        float p = 0.f;
#pragma unroll
        for (int i = 0; i < 7; ++i) p += sig4(v[i], ms);
        if (v7) p += sig4(v[7], ms);
        p = wsum(p);
        if (lane == 0) red[0][wid] = p;
        __syncthreads();
        float s = 0.f;
#pragma unroll
        for (int w = 0; w < 16; ++w) s += red[0][w];  // uniform -> same branch
        if (s < KF) lo = mid; else hi = mid;
        __syncthreads();
    }

    // ---- differentiable-Newton polish pass ----
    const float nu0 = 0.5f * (lo + hi);
    const float ns  = nu0 * NEGLOG2E;
    float sg = 0.f, sgp = 0.f;
#pragma unroll
    for (int i = 0; i < 7; ++i) {
        float s0;
        s0 = sig1(v[i].x, ns); sg += s0; sgp += s0 * (1.0f - s0);
        s0 = sig1(v[i].y, ns); sg += s0; sgp += s0 * (1.0f - s0);
        s0 = sig1(v[i].z, ns); sg += s0; sgp += s0 * (1.0f - s0);
        s0 = sig1(v[i].w, ns); sg += s0; sgp += s0 * (1.0f - s0);
    }
    if (v7) {
        float s0;
        s0 = sig1(v[7].x, ns); sg += s0; sgp += s0 * (1.0f - s0);
        s0 = sig1(v[7].y, ns); sg += s0; sgp += s0 * (1.0f - s0);
        s0 = sig1(v[7].z, ns); sg += s0; sgp += s0 * (1.0f - s0);
        s0 = sig1(v[7].w, ns); sg += s0; sgp += s0 * (1.0f - s0);
    }
    sg = wsum(sg); sgp = wsum(sgp);
    if (lane == 0) { red[0][wid] = sg; red[1][wid] = sgp; }
    __syncthreads();
    if (t == 0) {
        float g = 0.f, gp = 0.f;
#pragma unroll
        for (int w = 0; w < 16; ++w) { g += red[0][w]; gp += red[1][w]; }
        g -= KF;
        const float nu = nu0 - g / (gp + 1e-12f);
        const int yi = y[row];
        const float zt = x[(size_t)row * C + yi] * inv;
        const float u  = zt + nu;
        const float pt = 1.0f / (1.0f + __expf(-u));
        row_loss[row] = -__logf(pt + 1e-8f);
    }
}

__global__ __launch_bounds__(1024, 1) void sqp_mean(
    const float* __restrict__ rl, float* __restrict__ out, int n)
{
    float v = 0.f;
    for (int i = threadIdx.x; i < n; i += 1024) v += rl[i];
    v = wsum(v);
    __shared__ float red[16];
    const int wid = threadIdx.x >> 6, lane = threadIdx.x & 63;
    if (lane == 0) red[wid] = v;
    __syncthreads();
    if (threadIdx.x == 0) {
        float s = 0.f;
#pragma unroll
        for (int w = 0; w < 16; ++w) s += red[w];
        out[0] = s / (float)n;
    }
}

extern "C" void kernel_launch(void* const* d_in, const int* in_sizes, int n_in,
                              void* d_out, int out_size, void* d_ws, size_t ws_size,
                              hipStream_t stream) {
    const float* x = (const float*)d_in[0];
    const int*   y = (const int*)d_in[1];
    float* out = (float*)d_out;
    float* rl  = (float*)d_ws;           // per-row losses (rows * 4 bytes)
    const int rows = in_sizes[1];        // 2048

    sqp_rows<<<rows, TPB, 0, stream>>>(x, y, rl);
    sqp_mean<<<1, 1024, 0, stream>>>(rl, out, rows);
}

// Round 2
// 119.492 us; speedup vs baseline: 6.8754x; 6.8754x over previous
//
#include <hip/hip_runtime.h>
#include <math.h>

// SQP entropy-knapsack loss, MI355X (gfx950), round 2.
// One 1024-thread block per row; row held in 8 float4 regs as e_i = exp(-z_i).
// Root-find: bracketed log-Newton (nu -= ln(S/K)), 10 iters + 1 g/gp polish,
// instead of 50 bisections. Each pass: fma + rcp + add per element (1 trans op).

constexpr int   C      = 32000;
constexpr int   TPB    = 1024;
constexpr float KF     = 5.0f;
constexpr int   NIT    = 10;
constexpr float LOG2E  = 1.4426950408889634f;

__device__ __forceinline__ float wsum(float v) {
#pragma unroll
    for (int o = 32; o > 0; o >>= 1) v += __shfl_xor(v, o, 64);
    return v;
}

__global__ __launch_bounds__(TPB, 8) void sqp_rows(
    const float* __restrict__ x, const int* __restrict__ y,
    float* __restrict__ row_loss)
{
    const int row  = blockIdx.x;
    const int t    = threadIdx.x;
    const int wid  = t >> 6;
    const int lane = t & 63;
    const float4* xr = reinterpret_cast<const float4*>(x + (size_t)row * C);
    const bool v7 = (t + 7 * TPB) < (C / 4);   // t < 832; 832 = 13*64 -> wave-uniform

    // ---- load row (coalesced 16B/lane) ----
    float4 e[8];
#pragma unroll
    for (int i = 0; i < 7; ++i) e[i] = xr[t + i * TPB];
    e[7] = v7 ? xr[t + 7 * TPB] : make_float4(0.f, 0.f, 0.f, 0.f);

    // ---- sum of squares for the L2 norm ----
    float ss = 0.f;
#pragma unroll
    for (int i = 0; i < 8; ++i)
        ss += e[i].x*e[i].x + e[i].y*e[i].y + e[i].z*e[i].z + e[i].w*e[i].w;

    __shared__ float redss[16];
    __shared__ float redg[2][16];
    __shared__ float redgp[16];

    ss = wsum(ss);
    if (lane == 0) redss[wid] = ss;
    __syncthreads();
    float tss = 0.f;
#pragma unroll
    for (int w = 0; w < 16; ++w) tss += redss[w];
    const float inv = 1.0f / fmaxf(sqrtf(tss), 1e-12f);

    // ---- e_i = exp(-z_i) = exp2(-x_i * inv * log2e), in place ----
    const float sc = -inv * LOG2E;
#pragma unroll
    for (int i = 0; i < 8; ++i) {
        e[i].x = __builtin_amdgcn_exp2f(e[i].x * sc);
        e[i].y = __builtin_amdgcn_exp2f(e[i].y * sc);
        e[i].z = __builtin_amdgcn_exp2f(e[i].z * sc);
        e[i].w = __builtin_amdgcn_exp2f(e[i].w * sc);
    }
    // pad elements (i=7, !v7) now hold exp(0)=1 but are guarded below.

    // ---- bracketed log-Newton: nu <- nu - ln(S/K), bracket [-11, 11] ----
    // |z_i| <= 1 after normalization: S(-11) <= 32000*sig(-10) = 1.45 < K,
    // S(+11) >= 32000*sig(10) >> K, so the bracket always contains the root.
    float lo = -11.f, hi = 11.f, nu = 0.f;
    for (int it = 0; it < NIT; ++it) {
        const float D = __builtin_amdgcn_exp2f(-nu * LOG2E);   // exp(-nu)
        float g = 0.f;
#pragma unroll
        for (int i = 0; i < 7; ++i) {
            g += __builtin_amdgcn_rcpf(fmaf(e[i].x, D, 1.f));
            g += __builtin_amdgcn_rcpf(fmaf(e[i].y, D, 1.f));
            g += __builtin_amdgcn_rcpf(fmaf(e[i].z, D, 1.f));
            g += __builtin_amdgcn_rcpf(fmaf(e[i].w, D, 1.f));
        }
        if (v7) {
            g += __builtin_amdgcn_rcpf(fmaf(e[7].x, D, 1.f));
            g += __builtin_amdgcn_rcpf(fmaf(e[7].y, D, 1.f));
            g += __builtin_amdgcn_rcpf(fmaf(e[7].z, D, 1.f));
            g += __builtin_amdgcn_rcpf(fmaf(e[7].w, D, 1.f));
        }
        g = wsum(g);
        const int b = it & 1;
        if (lane == 0) redg[b][wid] = g;
        __syncthreads();
        float S = 0.f;
#pragma unroll
        for (int w = 0; w < 16; ++w) S += redg[b][w];   // identical order -> uniform
        if (S < KF) lo = nu; else hi = nu;
        // log-Newton candidate: exact fixed point when p_i << 1 (holds near root)
        const float cand = nu - __builtin_amdgcn_logf(S * (1.0f / KF)) * (1.0f / LOG2E);
        nu = (cand > lo && cand < hi) ? cand : 0.5f * (lo + hi);
    }

    // ---- final differentiable-Newton polish (mirrors reference) ----
    {
        const float D = __builtin_amdgcn_exp2f(-nu * LOG2E);
        float g = 0.f, gp = 0.f;
#pragma unroll
        for (int i = 0; i < 7; ++i) {
            float s;
            s = __builtin_amdgcn_rcpf(fmaf(e[i].x, D, 1.f)); g += s; gp = fmaf(s, 1.f - s, gp);
            s = __builtin_amdgcn_rcpf(fmaf(e[i].y, D, 1.f)); g += s; gp = fmaf(s, 1.f - s, gp);
            s = __builtin_amdgcn_rcpf(fmaf(e[i].z, D, 1.f)); g += s; gp = fmaf(s, 1.f - s, gp);
            s = __builtin_amdgcn_rcpf(fmaf(e[i].w, D, 1.f)); g += s; gp = fmaf(s, 1.f - s, gp);
        }
        if (v7) {
            float s;
            s = __builtin_amdgcn_rcpf(fmaf(e[7].x, D, 1.f)); g += s; gp = fmaf(s, 1.f - s, gp);
            s = __builtin_amdgcn_rcpf(fmaf(e[7].y, D, 1.f)); g += s; gp = fmaf(s, 1.f - s, gp);
            s = __builtin_amdgcn_rcpf(fmaf(e[7].z, D, 1.f)); g += s; gp = fmaf(s, 1.f - s, gp);
            s = __builtin_amdgcn_rcpf(fmaf(e[7].w, D, 1.f)); g += s; gp = fmaf(s, 1.f - s, gp);
        }
        g = wsum(g); gp = wsum(gp);
        if (lane == 0) { redg[0][wid] = g; redgp[wid] = gp; }
        __syncthreads();
        if (t == 0) {
            float gt = 0.f, gpt = 0.f;
#pragma unroll
            for (int w = 0; w < 16; ++w) { gt += redg[0][w]; gpt += redgp[w]; }
            gt -= KF;
            const float nuf = nu - gt / (gpt + 1e-12f);
            const int yi = y[row];
            const float zt = x[(size_t)row * C + yi] * inv;
            const float pt = 1.0f / (1.0f + __expf(-(zt + nuf)));
            row_loss[row] = -__logf(pt + 1e-8f);
        }
    }
}

__global__ __launch_bounds__(1024, 1) void sqp_mean(
    const float* __restrict__ rl, float* __restrict__ out, int n)
{
    float v = 0.f;
    for (int i = threadIdx.x; i < n; i += 1024) v += rl[i];
    v = wsum(v);
    __shared__ float red[16];
    const int wid = threadIdx.x >> 6, lane = threadIdx.x & 63;
    if (lane == 0) red[wid] = v;
    __syncthreads();
    if (threadIdx.x == 0) {
        float s = 0.f;
#pragma unroll
        for (int w = 0; w < 16; ++w) s += red[w];
        out[0] = s / (float)n;
    }
}

extern "C" void kernel_launch(void* const* d_in, const int* in_sizes, int n_in,
                              void* d_out, int out_size, void* d_ws, size_t ws_size,
                              hipStream_t stream) {
    const float* x = (const float*)d_in[0];
    const int*   y = (const int*)d_in[1];
    float* out = (float*)d_out;
    float* rl  = (float*)d_ws;           // per-row losses
    const int rows = in_sizes[1];        // 2048

    sqp_rows<<<rows, TPB, 0, stream>>>(x, y, rl);
    sqp_mean<<<1, 1024, 0, stream>>>(rl, out, rows);
}

// Round 3
// 55.359 us; speedup vs baseline: 14.8404x; 2.1585x over previous
//
#include <hip/hip_runtime.h>
#include <math.h>

// SQP entropy-knapsack loss, MI355X (gfx950), round 3.
// One 1024-thread block per row, row in 8 float4 regs.
// Closed-form linearized solve: nu1 = ln(K/E), E = sum exp(z_i)  (fused into
// the exp pass); one log-Newton refinement; one g/gp differentiable-Newton
// polish. D = exp(-nu) propagated algebraically (D1=E/K, D2=D1*S1/K) so no
// scalar exp is ever taken. 4 transcendental ops/element total (was 12).

constexpr int   C     = 32000;
constexpr int   TPB   = 1024;
constexpr float KF    = 5.0f;
constexpr float LOG2E = 1.4426950408889634f;
constexpr float LN2   = 0.6931471805599453f;

__device__ __forceinline__ float wsum(float v) {
#pragma unroll
    for (int o = 32; o > 0; o >>= 1) v += __shfl_xor(v, o, 64);
    return v;
}

__global__ __launch_bounds__(TPB, 8) void sqp_rows(
    const float* __restrict__ x, const int* __restrict__ y,
    float* __restrict__ row_loss)
{
    const int row  = blockIdx.x;
    const int t    = threadIdx.x;
    const int wid  = t >> 6;
    const int lane = t & 63;
    const float4* xr = reinterpret_cast<const float4*>(x + (size_t)row * C);
    const bool v7 = (t + 7 * TPB) < (C / 4);   // t < 832 (13 full waves) -> wave-uniform

    __shared__ float bufS[16];
    __shared__ float buf0[16];
    __shared__ float buf1[16];
    __shared__ float bufgp[16];

    // ---- load row (coalesced 16B/lane) ----
    float4 e[8];
#pragma unroll
    for (int i = 0; i < 7; ++i) e[i] = xr[t + i * TPB];
    e[7] = v7 ? xr[t + 7 * TPB] : make_float4(0.f, 0.f, 0.f, 0.f);

    // ---- pass 0: sum of squares -> L2 norm ----
    float ss = 0.f;
#pragma unroll
    for (int i = 0; i < 8; ++i)
        ss += e[i].x*e[i].x + e[i].y*e[i].y + e[i].z*e[i].z + e[i].w*e[i].w;
    ss = wsum(ss);
    if (lane == 0) bufS[wid] = ss;
    __syncthreads();
    float tss = 0.f;
#pragma unroll
    for (int w = 0; w < 16; ++w) tss += bufS[w];
    const float inv = 1.0f / fmaxf(sqrtf(tss), 1e-12f);

    // ---- pass A (fused): e_i = exp(-z_i), E = sum exp(+z_i) ----
    const float sc = -inv * LOG2E;
    float E = 0.f;
#pragma unroll
    for (int i = 0; i < 8; ++i) {
        e[i].x = __builtin_amdgcn_exp2f(e[i].x * sc);
        e[i].y = __builtin_amdgcn_exp2f(e[i].y * sc);
        e[i].z = __builtin_amdgcn_exp2f(e[i].z * sc);
        e[i].w = __builtin_amdgcn_exp2f(e[i].w * sc);
        if (i < 7 || v7) {
            E += __builtin_amdgcn_rcpf(e[i].x);
            E += __builtin_amdgcn_rcpf(e[i].y);
            E += __builtin_amdgcn_rcpf(e[i].z);
            E += __builtin_amdgcn_rcpf(e[i].w);
        }
    }
    E = wsum(E);
    if (lane == 0) buf0[wid] = E;
    __syncthreads();
    float Et = 0.f;
#pragma unroll
    for (int w = 0; w < 16; ++w) Et += buf0[w];

    // nu1 = ln(K/E);  D1 = exp(-nu1) = E/K exactly (no scalar exp needed)
    const float D1 = Et * (1.0f / KF);

    // ---- pass B: S1 = sum sigmoid(z + nu1) ----
    float g1 = 0.f;
#pragma unroll
    for (int i = 0; i < 7; ++i) {
        g1 += __builtin_amdgcn_rcpf(fmaf(e[i].x, D1, 1.f));
        g1 += __builtin_amdgcn_rcpf(fmaf(e[i].y, D1, 1.f));
        g1 += __builtin_amdgcn_rcpf(fmaf(e[i].z, D1, 1.f));
        g1 += __builtin_amdgcn_rcpf(fmaf(e[i].w, D1, 1.f));
    }
    if (v7) {
        g1 += __builtin_amdgcn_rcpf(fmaf(e[7].x, D1, 1.f));
        g1 += __builtin_amdgcn_rcpf(fmaf(e[7].y, D1, 1.f));
        g1 += __builtin_amdgcn_rcpf(fmaf(e[7].z, D1, 1.f));
        g1 += __builtin_amdgcn_rcpf(fmaf(e[7].w, D1, 1.f));
    }
    g1 = wsum(g1);
    if (lane == 0) buf1[wid] = g1;
    __syncthreads();
    float S1 = 0.f;
#pragma unroll
    for (int w = 0; w < 16; ++w) S1 += buf1[w];

    // log-Newton: nu2 = nu1 - ln(S1/K);  D2 = D1 * S1/K  (again no exp)
    const float D2 = D1 * (S1 * (1.0f / KF));

    // ---- pass C: g, gp at nu2 (differentiable-Newton polish) ----
    float g = 0.f, gp = 0.f;
#pragma unroll
    for (int i = 0; i < 7; ++i) {
        float s;
        s = __builtin_amdgcn_rcpf(fmaf(e[i].x, D2, 1.f)); g += s; gp = fmaf(s, 1.f - s, gp);
        s = __builtin_amdgcn_rcpf(fmaf(e[i].y, D2, 1.f)); g += s; gp = fmaf(s, 1.f - s, gp);
        s = __builtin_amdgcn_rcpf(fmaf(e[i].z, D2, 1.f)); g += s; gp = fmaf(s, 1.f - s, gp);
        s = __builtin_amdgcn_rcpf(fmaf(e[i].w, D2, 1.f)); g += s; gp = fmaf(s, 1.f - s, gp);
    }
    if (v7) {
        float s;
        s = __builtin_amdgcn_rcpf(fmaf(e[7].x, D2, 1.f)); g += s; gp = fmaf(s, 1.f - s, gp);
        s = __builtin_amdgcn_rcpf(fmaf(e[7].y, D2, 1.f)); g += s; gp = fmaf(s, 1.f - s, gp);
        s = __builtin_amdgcn_rcpf(fmaf(e[7].z, D2, 1.f)); g += s; gp = fmaf(s, 1.f - s, gp);
        s = __builtin_amdgcn_rcpf(fmaf(e[7].w, D2, 1.f)); g += s; gp = fmaf(s, 1.f - s, gp);
    }
    g = wsum(g); gp = wsum(gp);
    if (lane == 0) { buf0[wid] = g; bufgp[wid] = gp; }
    __syncthreads();
    if (t == 0) {
        float gt = 0.f, gpt = 0.f;
#pragma unroll
        for (int w = 0; w < 16; ++w) { gt += buf0[w]; gpt += bufgp[w]; }
        const float nu2 = -__builtin_amdgcn_logf(D2) * LN2;  // ln(1/D2)
        const float nuf = nu2 - (gt - KF) / (gpt + 1e-12f);
        const int yi = y[row];
        const float zt = x[(size_t)row * C + yi] * inv;
        const float pt = 1.0f / (1.0f + __expf(-(zt + nuf)));
        row_loss[row] = -__logf(pt + 1e-8f);
    }
}

__global__ __launch_bounds__(256, 1) void sqp_mean(
    const float* __restrict__ rl, float* __restrict__ out, int n)
{
    float v = 0.f;
    for (int i = threadIdx.x; i < n; i += 256) v += rl[i];
    v = wsum(v);
    __shared__ float red[4];
    const int wid = threadIdx.x >> 6, lane = threadIdx.x & 63;
    if (lane == 0) red[wid] = v;
    __syncthreads();
    if (threadIdx.x == 0) {
        float s = 0.f;
#pragma unroll
        for (int w = 0; w < 4; ++w) s += red[w];
        out[0] = s / (float)n;
    }
}

extern "C" void kernel_launch(void* const* d_in, const int* in_sizes, int n_in,
                              void* d_out, int out_size, void* d_ws, size_t ws_size,
                              hipStream_t stream) {
    const float* x = (const float*)d_in[0];
    const int*   y = (const int*)d_in[1];
    float* out = (float*)d_out;
    float* rl  = (float*)d_ws;           // per-row losses
    const int rows = in_sizes[1];        // 2048

    sqp_rows<<<rows, TPB, 0, stream>>>(x, y, rl);
    sqp_mean<<<1, 256, 0, stream>>>(rl, out, rows);
}